// Round 1
// baseline (294.830 us; speedup 1.0000x reference)
//
#include <hip/hip_runtime.h>

// YOLO v1 loss, single-pass with last-block-done finalization.
// B=16384, S2=49, C=30  ->  N = 802816 rows of 30 f32.
#define NROWS 802816
#define RPB   512          // rows per block
#define NB    (NROWS/RPB)  // 1568 blocks (exact)
#define BS    256          // threads per block
#define SCAN_N 2048        // next pow2 >= NB

struct RowRes { float term; bool mask; };

__device__ __forceinline__ float iou_f(float ax, float ay, float aX, float aY,
                                       float bx, float by, float bX, float bY) {
    float ltx = fmaxf(ax, bx), lty = fmaxf(ay, by);
    float rbx = fminf(aX, bX), rby = fminf(aY, bY);
    float w = fmaxf(rbx - ltx, 0.0f), h = fmaxf(rby - lty, 0.0f);
    float inter = w * h;
    float aa = (aX - ax) * (aY - ay);
    float ab = (bX - bx) * (bY - by);
    return inter / (aa + ab - inter);
}

// Per-row loss term + mask. Row stride 120 B is always 8B-aligned -> float2 loads.
__device__ __forceinline__ RowRes row_term(const float* __restrict__ P,
                                           const float* __restrict__ T, int r) {
    const float2* pr = reinterpret_cast<const float2*>(P + (size_t)r * 30);
    float2 a0 = pr[0], a1 = pr[1], a2 = pr[2], a3 = pr[3], a4 = pr[4]; // p0..p9
    const float2* tr = reinterpret_cast<const float2*>(T + (size_t)r * 30);
    float2 b0 = tr[0], b1 = tr[1], b2 = tr[2], b3 = tr[3], b4 = tr[4]; // t0..t9

    bool mask = (b2.x == 1.0f); // t[:,4]

    // box0 = p[0:4], box1 = p[5:9], tb = t[0:4]
    float i0 = iou_f(a0.x, a0.y, a1.x, a1.y, b0.x, b0.y, b1.x, b1.y);
    float i1 = iou_f(a2.y, a3.x, a3.y, a4.x, b0.x, b0.y, b1.x, b1.y);
    bool ch = i1 > i0;
    float miou = fmaxf(i0, i1);

    float px = ch ? a2.y : a0.x;
    float py = ch ? a3.x : a0.y;
    float pw = ch ? a3.y : a1.x;
    float ph = ch ? a4.x : a1.y;
    // tc = choose1 ? t[5:9] : t[0:4]
    float tx = ch ? b2.y : b0.x;
    float ty = ch ? b3.x : b0.y;
    float tw = ch ? b3.y : b1.x;
    float th = ch ? b4.x : b1.y;
    float cf = ch ? a4.y : a2.y; // p9 : p5

    float dx = px - tx, dy = py - ty, dw = pw - tw, dh = ph - th;
    float dc = cf - miou;
    RowRes rr;
    rr.term = dx * dx + dy * dy + dw * dw + dh * dh + 2.0f * dc * dc;
    rr.mask = mask;
    return rr;
}

__global__ __launch_bounds__(BS) void yolo_loss_kernel(
        const float* __restrict__ P, const float* __restrict__ T,
        float* __restrict__ out, int* __restrict__ done,
        float* __restrict__ sums, int* __restrict__ counts) {
    __shared__ float s_f[4];
    __shared__ float s_f2[4];
    __shared__ int   s_i[4];
    __shared__ int   s_flag;
    __shared__ int   s_bb, s_take;
    __shared__ int   sA[SCAN_N], sB[SCAN_N];

    const int tid = threadIdx.x;
    const int b = blockIdx.x;
    const int lane = tid & 63, wv = tid >> 6;
    const int base = b * RPB;

    // ---- main pass: per-block masked count + masked term sum ----
    float acc = 0.0f;
    int cnt = 0;
#pragma unroll
    for (int j = 0; j < RPB / BS; ++j) {
        RowRes rr = row_term(P, T, base + j * BS + tid);
        if (rr.mask) { acc += rr.term; cnt++; }
    }
#pragma unroll
    for (int o = 32; o > 0; o >>= 1) {
        acc += __shfl_down(acc, o, 64);
        cnt += __shfl_down(cnt, o, 64);
    }
    if (lane == 0) { s_f[wv] = acc; s_i[wv] = cnt; }
    __syncthreads();
    if (tid == 0) {
        sums[b]   = s_f[0] + s_f[1] + s_f[2] + s_f[3];
        counts[b] = s_i[0] + s_i[1] + s_i[2] + s_i[3];
        __threadfence();                       // release: publish sums/counts
        int prev = atomicAdd(done, 1);
        s_flag = (prev == NB - 1);
    }
    __syncthreads();
    if (!s_flag) return;

    // ---- final phase: only the last-finishing block gets here ----
    __threadfence();                           // acquire: see others' writes

    // inclusive scan of counts in LDS (Hillis-Steele, padded to 2048)
    for (int i = tid; i < SCAN_N; i += BS) sA[i] = (i < NB) ? counts[i] : 0;
    __syncthreads();
    int* src = sA; int* dst = sB;
    for (int off = 1; off < SCAN_N; off <<= 1) {
        for (int i = tid; i < SCAN_N; i += BS) {
            int v = src[i];
            if (i >= off) v += src[i - off];
            dst[i] = v;
        }
        __syncthreads();
        int* t_ = src; src = dst; dst = t_;
    }
    const int n  = src[SCAN_N - 1];
    const int nh = n >> 1;                     // n // 2

    if (tid == 0) { s_bb = -1; s_take = 0; }
    __syncthreads();

    // full blocks: P_b + c_b <= nh contribute sums[b]; one boundary block is partial
    float fs = 0.0f;
    for (int i = tid; i < NB; i += BS) {
        int incl = src[i];
        int c = incl - ((i > 0) ? src[i - 1] : 0);
        int pfx = incl - c;
        int take = nh - pfx;
        take = take < 0 ? 0 : (take > c ? c : take);
        if (take == c)      fs += sums[i];
        else if (take > 0) { s_bb = i; s_take = take; }  // exactly one
    }
    __syncthreads();
#pragma unroll
    for (int o = 32; o > 0; o >>= 1) fs += __shfl_down(fs, o, 64);
    if (lane == 0) s_f[wv] = fs;
    __syncthreads();

    // boundary block: recompute its 512 rows in order, take first `take` masked terms
    const int bb = s_bb, take = s_take;
    float psum = 0.0f;
    if (bb >= 0) {
        int run = 0;
        for (int j = 0; j < RPB / BS; ++j) {
            RowRes rr = row_term(P, T, bb * RPB + j * BS + tid);
            unsigned long long bal = __ballot(rr.mask);
            if (lane == 0) s_i[wv] = __popcll(bal);
            __syncthreads();
            int off = run;
            for (int w = 0; w < wv; ++w) off += s_i[w];
            int rk = off + __popcll(bal & ((1ull << lane) - 1ull));
            if (rr.mask && rk < take) psum += rr.term;
            run += s_i[0] + s_i[1] + s_i[2] + s_i[3];
            __syncthreads();
        }
    }
#pragma unroll
    for (int o = 32; o > 0; o >>= 1) psum += __shfl_down(psum, o, 64);
    if (lane == 0) s_f2[wv] = psum;
    __syncthreads();

    if (tid == 0) {
        float total = s_f[0] + s_f[1] + s_f[2] + s_f[3]
                    + s_f2[0] + s_f2[1] + s_f2[2] + s_f2[3];
        out[0] = 5.0f * total;                 // LAMBDA_COORD * (se_xy + se_wh + 2*se_conf)
    }
}

extern "C" void kernel_launch(void* const* d_in, const int* in_sizes, int n_in,
                              void* d_out, int out_size, void* d_ws, size_t ws_size,
                              hipStream_t stream) {
    const float* P = (const float*)d_in[0];   // predictions f32
    const float* T = (const float*)d_in[1];   // targets f32
    float* out = (float*)d_out;

    int*   done   = (int*)d_ws;                          // [0,4): done counter
    float* sums   = (float*)((char*)d_ws + 64);          // NB floats
    int*   counts = (int*)((char*)d_ws + 64 + NB * 4);   // NB ints

    hipMemsetAsync(d_ws, 0, 64, stream);      // zero the done counter (ws is poisoned)
    yolo_loss_kernel<<<NB, BS, 0, stream>>>(P, T, out, done, sums, counts);
}

// Round 4
// 291.772 us; speedup vs baseline: 1.0105x; 1.0105x over previous
//
#include <hip/hip_runtime.h>

// YOLO v1 loss, single-pass with last-block-done finalization.
// R2: LDS-staged coalesced loads (needed columns only). R1 was request-rate
// bound (165us @ 9% HBM BW, VALUBusy 1.4%; replay dispatches with L3-resident
// inputs were equally slow -> latency/request bound, not BW bound).
// Line-request arithmetic: both tensors = 1.5M 128B lines total -> 960/block
// structural minimum; this staging scheme achieves exactly that (~12 lines
// per wave-load x 20 loads x 4 waves).
// B=16384, S2=49, C=30  ->  N = 802816 rows of 30 f32.
#define NROWS 802816
#define RPB   512          // rows per block
#define NB    (NROWS/RPB)  // 1568 blocks (exact)
#define BS    256          // threads per block
#define TILE  256          // rows staged per iteration (2 iterations/block)
#define SCAN_N 2048        // next pow2 >= NB

struct RowRes { float term; bool mask; };

__device__ __forceinline__ float iou_f(float ax, float ay, float aX, float aY,
                                       float bx, float by, float bX, float bY) {
    float ltx = fmaxf(ax, bx), lty = fmaxf(ay, by);
    float rbx = fminf(aX, bX), rby = fminf(aY, bY);
    float w = fmaxf(rbx - ltx, 0.0f), h = fmaxf(rby - lty, 0.0f);
    float inter = w * h;
    float aa = (aX - ax) * (aY - ay);
    float ab = (bX - bx) * (bY - by);
    return inter / (aa + ab - inter);
}

// Loss term from the 10 leading floats of p-row (a0..a4) and t-row (b0..b4).
__device__ __forceinline__ RowRes term_from(float2 a0, float2 a1, float2 a2,
                                            float2 a3, float2 a4, float2 b0,
                                            float2 b1, float2 b2, float2 b3,
                                            float2 b4) {
    bool mask = (b2.x == 1.0f); // t[:,4]
    float i0 = iou_f(a0.x, a0.y, a1.x, a1.y, b0.x, b0.y, b1.x, b1.y);
    float i1 = iou_f(a2.y, a3.x, a3.y, a4.x, b0.x, b0.y, b1.x, b1.y);
    bool ch = i1 > i0;
    float miou = fmaxf(i0, i1);

    float px = ch ? a2.y : a0.x;
    float py = ch ? a3.x : a0.y;
    float pw = ch ? a3.y : a1.x;
    float ph = ch ? a4.x : a1.y;
    float tx = ch ? b2.y : b0.x;
    float ty = ch ? b3.x : b0.y;
    float tw = ch ? b3.y : b1.x;
    float th = ch ? b4.x : b1.y;
    float cf = ch ? a4.y : a2.y; // p9 : p5

    float dx = px - tx, dy = py - ty, dw = pw - tw, dh = ph - th;
    float dc = cf - miou;
    RowRes rr;
    rr.term = dx * dx + dy * dy + dw * dw + dh * dh + 2.0f * dc * dc;
    rr.mask = mask;
    return rr;
}

// Direct-from-global row term (used only for the 512-row boundary recompute).
__device__ __forceinline__ RowRes row_term(const float* __restrict__ P,
                                           const float* __restrict__ T, int r) {
    const float2* pr = reinterpret_cast<const float2*>(P + (size_t)r * 30);
    const float2* tr = reinterpret_cast<const float2*>(T + (size_t)r * 30);
    return term_from(pr[0], pr[1], pr[2], pr[3], pr[4],
                     tr[0], tr[1], tr[2], tr[3], tr[4]);
}

__global__ __launch_bounds__(BS) void yolo_loss_kernel(
        const float* __restrict__ P, const float* __restrict__ T,
        float* __restrict__ out, int* __restrict__ done,
        float* __restrict__ sums, int* __restrict__ counts) {
    // Stage buffer (20480 B) unioned with the scan arrays (16384 B): the scan
    // only runs in the final block, after its staging use is over.
    __shared__ __align__(16) char s_buf[TILE * 5 * 8 * 2];
    float2* sP = reinterpret_cast<float2*>(s_buf);
    float2* sT = reinterpret_cast<float2*>(s_buf + TILE * 5 * 8);
    int* sA = reinterpret_cast<int*>(s_buf);
    int* sB = reinterpret_cast<int*>(s_buf + SCAN_N * 4);

    __shared__ float s_f[4];
    __shared__ float s_f2[4];
    __shared__ int   s_i[4];
    __shared__ int   s_flag;
    __shared__ int   s_bb, s_take;

    const int tid = threadIdx.x;
    const int b = blockIdx.x;
    const int lane = tid & 63, wv = tid >> 6;

    const float2* Pg = reinterpret_cast<const float2*>(P);
    const float2* Tg = reinterpret_cast<const float2*>(T);

    // ---- main pass: per-block masked count + masked term sum ----
    float acc = 0.0f;
    int cnt = 0;
#pragma unroll
    for (int tile = 0; tile < RPB / TILE; ++tile) {
        // Stage: needed float2 index n in [0, TILE*5); row=n/5, col2=n%5.
        // Consecutive lanes -> consecutive n -> near-contiguous global bytes
        // (40B runs with 80B gaps): ~12 lines per wave-load vs ~60 before.
        const size_t base2 = (size_t)(b * RPB + tile * TILE) * 15;
#pragma unroll
        for (int k = 0; k < TILE * 5 / BS; ++k) {
            unsigned n = tid + k * BS;
            unsigned row = n / 5u, c = n - row * 5u;
            size_t g = base2 + row * 15u + c;
            sP[n] = Pg[g];
            sT[n] = Tg[g];
        }
        __syncthreads();
        RowRes rr = term_from(sP[tid * 5 + 0], sP[tid * 5 + 1], sP[tid * 5 + 2],
                              sP[tid * 5 + 3], sP[tid * 5 + 4],
                              sT[tid * 5 + 0], sT[tid * 5 + 1], sT[tid * 5 + 2],
                              sT[tid * 5 + 3], sT[tid * 5 + 4]);
        if (rr.mask) { acc += rr.term; cnt++; }
        __syncthreads();   // buffer reused next tile / by scan
    }
#pragma unroll
    for (int o = 32; o > 0; o >>= 1) {
        acc += __shfl_down(acc, o, 64);
        cnt += __shfl_down(cnt, o, 64);
    }
    if (lane == 0) { s_f[wv] = acc; s_i[wv] = cnt; }
    __syncthreads();
    if (tid == 0) {
        sums[b]   = s_f[0] + s_f[1] + s_f[2] + s_f[3];
        counts[b] = s_i[0] + s_i[1] + s_i[2] + s_i[3];
        __threadfence();                       // release: publish sums/counts
        int prev = atomicAdd(done, 1);
        s_flag = (prev == NB - 1);
    }
    __syncthreads();
    if (!s_flag) return;

    // ---- final phase: only the last-finishing block gets here ----
    __threadfence();                           // acquire: see others' writes

    // inclusive scan of counts in LDS (Hillis-Steele, padded to 2048)
    for (int i = tid; i < SCAN_N; i += BS) sA[i] = (i < NB) ? counts[i] : 0;
    __syncthreads();
    int* src = sA; int* dst = sB;
    for (int off = 1; off < SCAN_N; off <<= 1) {
        for (int i = tid; i < SCAN_N; i += BS) {
            int v = src[i];
            if (i >= off) v += src[i - off];
            dst[i] = v;
        }
        __syncthreads();
        int* t_ = src; src = dst; dst = t_;
    }
    const int n  = src[SCAN_N - 1];
    const int nh = n >> 1;                     // n // 2

    if (tid == 0) { s_bb = -1; s_take = 0; }
    __syncthreads();

    // full blocks with prefix+count <= nh contribute sums[b]; one is partial
    float fs = 0.0f;
    for (int i = tid; i < NB; i += BS) {
        int incl = src[i];
        int c = incl - ((i > 0) ? src[i - 1] : 0);
        int pfx = incl - c;
        int take = nh - pfx;
        take = take < 0 ? 0 : (take > c ? c : take);
        if (take == c)      fs += sums[i];
        else if (take > 0) { s_bb = i; s_take = take; }  // exactly one
    }
    __syncthreads();
#pragma unroll
    for (int o = 32; o > 0; o >>= 1) fs += __shfl_down(fs, o, 64);
    if (lane == 0) s_f[wv] = fs;
    __syncthreads();

    // boundary block: recompute its 512 rows in order, take first `take` masked
    const int bb = s_bb, take = s_take;
    float psum = 0.0f;
    if (bb >= 0) {
        int run = 0;
        for (int j = 0; j < RPB / BS; ++j) {
            RowRes rr = row_term(P, T, bb * RPB + j * BS + tid);
            unsigned long long bal = __ballot(rr.mask);
            if (lane == 0) s_i[wv] = __popcll(bal);
            __syncthreads();
            int off = run;
            for (int w = 0; w < wv; ++w) off += s_i[w];
            int rk = off + __popcll(bal & ((1ull << lane) - 1ull));
            if (rr.mask && rk < take) psum += rr.term;
            run += s_i[0] + s_i[1] + s_i[2] + s_i[3];
            __syncthreads();
        }
    }
#pragma unroll
    for (int o = 32; o > 0; o >>= 1) psum += __shfl_down(psum, o, 64);
    if (lane == 0) s_f2[wv] = psum;
    __syncthreads();

    if (tid == 0) {
        float total = s_f[0] + s_f[1] + s_f[2] + s_f[3]
                    + s_f2[0] + s_f2[1] + s_f2[2] + s_f2[3];
        out[0] = 5.0f * total;                 // LAMBDA_COORD * (se_xy + se_wh + 2*se_conf)
    }
}

extern "C" void kernel_launch(void* const* d_in, const int* in_sizes, int n_in,
                              void* d_out, int out_size, void* d_ws, size_t ws_size,
                              hipStream_t stream) {
    const float* P = (const float*)d_in[0];   // predictions f32
    const float* T = (const float*)d_in[1];   // targets f32
    float* out = (float*)d_out;

    int*   done   = (int*)d_ws;                          // [0,4): done counter
    float* sums   = (float*)((char*)d_ws + 64);          // NB floats
    int*   counts = (int*)((char*)d_ws + 64 + NB * 4);   // NB ints

    hipMemsetAsync(d_ws, 0, 64, stream);      // zero the done counter (ws is poisoned)
    yolo_loss_kernel<<<NB, BS, 0, stream>>>(P, T, out, done, sums, counts);
}

// Round 5
// 215.232 us; speedup vs baseline: 1.3698x; 1.3556x over previous
//
#include <hip/hip_runtime.h>

// YOLO v1 loss — R5: two-kernel design, NO device fences / atomics.
// R4 finding: duration (~157us) was invariant to access pattern and data
// residency; WRITE_SIZE=147MB vs ~12KB actually written by the kernel.
// Diagnosis: per-block __threadfence() (device-scope => L2 writeback on
// non-coherent per-XCD L2s) forced writeback of the harness's 193MB d_in
// restore dirt, serialized across 1568 blocks => ~130us fixed cost.
// Fix: kernel boundary provides ordering/visibility once, off critical path.
// B=16384, S2=49, C=30  ->  N = 802816 rows of 30 f32.
#define NROWS 802816
#define RPB   512          // rows per block (kernel1)
#define NB    (NROWS/RPB)  // 1568 blocks (exact)
#define BS    256          // threads per block
#define SCAN_N 2048        // next pow2 >= NB

struct RowRes { float term; bool mask; };

__device__ __forceinline__ float iou_f(float ax, float ay, float aX, float aY,
                                       float bx, float by, float bX, float bY) {
    float ltx = fmaxf(ax, bx), lty = fmaxf(ay, by);
    float rbx = fminf(aX, bX), rby = fminf(aY, bY);
    float w = fmaxf(rbx - ltx, 0.0f), h = fmaxf(rby - lty, 0.0f);
    float inter = w * h;
    float aa = (aX - ax) * (aY - ay);
    float ab = (bX - bx) * (bY - by);
    return inter / (aa + ab - inter);
}

// Loss term from the 10 leading floats of p-row (a0..a4) and t-row (b0..b4).
__device__ __forceinline__ RowRes term_from(float2 a0, float2 a1, float2 a2,
                                            float2 a3, float2 a4, float2 b0,
                                            float2 b1, float2 b2, float2 b3,
                                            float2 b4) {
    bool mask = (b2.x == 1.0f); // t[:,4]
    float i0 = iou_f(a0.x, a0.y, a1.x, a1.y, b0.x, b0.y, b1.x, b1.y);
    float i1 = iou_f(a2.y, a3.x, a3.y, a4.x, b0.x, b0.y, b1.x, b1.y);
    bool ch = i1 > i0;
    float miou = fmaxf(i0, i1);

    float px = ch ? a2.y : a0.x;
    float py = ch ? a3.x : a0.y;
    float pw = ch ? a3.y : a1.x;
    float ph = ch ? a4.x : a1.y;
    float tx = ch ? b2.y : b0.x;
    float ty = ch ? b3.x : b0.y;
    float tw = ch ? b3.y : b1.x;
    float th = ch ? b4.x : b1.y;
    float cf = ch ? a4.y : a2.y; // p9 : p5

    float dx = px - tx, dy = py - ty, dw = pw - tw, dh = ph - th;
    float dc = cf - miou;
    RowRes rr;
    rr.term = dx * dx + dy * dy + dw * dw + dh * dh + 2.0f * dc * dc;
    rr.mask = mask;
    return rr;
}

// Direct-from-global row term (kernel2's 512-row boundary recompute only).
__device__ __forceinline__ RowRes row_term(const float* __restrict__ P,
                                           const float* __restrict__ T, int r) {
    const float2* pr = reinterpret_cast<const float2*>(P + (size_t)r * 30);
    const float2* tr = reinterpret_cast<const float2*>(T + (size_t)r * 30);
    return term_from(pr[0], pr[1], pr[2], pr[3], pr[4],
                     tr[0], tr[1], tr[2], tr[3], tr[4]);
}

// ---- kernel 1: per-block masked count + masked term sum (no fences) ----
__global__ __launch_bounds__(BS) void yolo_part1(
        const float* __restrict__ P, const float* __restrict__ T,
        float* __restrict__ sums, int* __restrict__ counts) {
    __shared__ __align__(16) float2 sP[RPB * 5];   // 20480 B
    __shared__ __align__(16) float2 sT[RPB * 5];   // 20480 B
    __shared__ float s_f[4];
    __shared__ int   s_i[4];

    const int tid = threadIdx.x;
    const int b = blockIdx.x;
    const int lane = tid & 63, wv = tid >> 6;

    const float2* Pg = reinterpret_cast<const float2*>(P);
    const float2* Tg = reinterpret_cast<const float2*>(T);

    // Stage all 512 rows' needed columns (first 5 float2 of each 15-float2
    // row): 20 independent coalesced-ish loads per thread before one barrier.
    const size_t base2 = (size_t)b * RPB * 15;
#pragma unroll
    for (int k = 0; k < RPB * 5 / BS; ++k) {       // 10 iterations
        unsigned n = tid + k * BS;
        unsigned row = n / 5u, c = n - row * 5u;
        size_t g = base2 + row * 15u + c;
        sP[n] = Pg[g];
        sT[n] = Tg[g];
    }
    __syncthreads();

    float acc = 0.0f;
    int cnt = 0;
#pragma unroll
    for (int j = 0; j < RPB / BS; ++j) {           // rows tid, tid+256
        int r = tid + j * BS;
        RowRes rr = term_from(sP[r * 5 + 0], sP[r * 5 + 1], sP[r * 5 + 2],
                              sP[r * 5 + 3], sP[r * 5 + 4],
                              sT[r * 5 + 0], sT[r * 5 + 1], sT[r * 5 + 2],
                              sT[r * 5 + 3], sT[r * 5 + 4]);
        if (rr.mask) { acc += rr.term; cnt++; }
    }
#pragma unroll
    for (int o = 32; o > 0; o >>= 1) {
        acc += __shfl_down(acc, o, 64);
        cnt += __shfl_down(cnt, o, 64);
    }
    if (lane == 0) { s_f[wv] = acc; s_i[wv] = cnt; }
    __syncthreads();
    if (tid == 0) {
        sums[b]   = s_f[0] + s_f[1] + s_f[2] + s_f[3];
        counts[b] = s_i[0] + s_i[1] + s_i[2] + s_i[3];
    }
}

// ---- kernel 2: one block — scan, select, boundary recompute, final sum ----
__global__ __launch_bounds__(BS) void yolo_part2(
        const float* __restrict__ P, const float* __restrict__ T,
        const float* __restrict__ sums, const int* __restrict__ counts,
        float* __restrict__ out) {
    __shared__ int sA[SCAN_N], sB[SCAN_N];         // 16 KB
    __shared__ float s_f[4], s_f2[4];
    __shared__ int   s_i[4];
    __shared__ int   s_bb, s_take;

    const int tid = threadIdx.x;
    const int lane = tid & 63, wv = tid >> 6;

    // inclusive scan of counts (Hillis-Steele over 2048, 256 threads)
    for (int i = tid; i < SCAN_N; i += BS) sA[i] = (i < NB) ? counts[i] : 0;
    __syncthreads();
    int* src = sA; int* dst = sB;
    for (int off = 1; off < SCAN_N; off <<= 1) {
        for (int i = tid; i < SCAN_N; i += BS) {
            int v = src[i];
            if (i >= off) v += src[i - off];
            dst[i] = v;
        }
        __syncthreads();
        int* t_ = src; src = dst; dst = t_;
    }
    const int n  = src[SCAN_N - 1];
    const int nh = n >> 1;                         // n // 2

    if (tid == 0) { s_bb = -1; s_take = 0; }
    __syncthreads();

    // full blocks with prefix+count <= nh contribute sums[i]; <=1 is partial
    float fs = 0.0f;
    for (int i = tid; i < NB; i += BS) {
        int incl = src[i];
        int c = incl - ((i > 0) ? src[i - 1] : 0);
        int pfx = incl - c;
        int take = nh - pfx;
        take = take < 0 ? 0 : (take > c ? c : take);
        if (take == c)      fs += sums[i];
        else if (take > 0) { s_bb = i; s_take = take; }  // exactly one
    }
    __syncthreads();
#pragma unroll
    for (int o = 32; o > 0; o >>= 1) fs += __shfl_down(fs, o, 64);
    if (lane == 0) s_f[wv] = fs;
    __syncthreads();

    // boundary block: recompute its 512 rows in order, take first `take` masked
    const int bb = s_bb, take = s_take;
    float psum = 0.0f;
    if (bb >= 0) {                                 // uniform branch
        int run = 0;
        for (int j = 0; j < RPB / BS; ++j) {
            RowRes rr = row_term(P, T, bb * RPB + j * BS + tid);
            unsigned long long bal = __ballot(rr.mask);
            if (lane == 0) s_i[wv] = __popcll(bal);
            __syncthreads();
            int off = run;
            for (int w = 0; w < wv; ++w) off += s_i[w];
            int rk = off + __popcll(bal & ((1ull << lane) - 1ull));
            if (rr.mask && rk < take) psum += rr.term;
            run += s_i[0] + s_i[1] + s_i[2] + s_i[3];
            __syncthreads();
        }
    }
#pragma unroll
    for (int o = 32; o > 0; o >>= 1) psum += __shfl_down(psum, o, 64);
    if (lane == 0) s_f2[wv] = psum;
    __syncthreads();

    if (tid == 0) {
        float total = s_f[0] + s_f[1] + s_f[2] + s_f[3]
                    + s_f2[0] + s_f2[1] + s_f2[2] + s_f2[3];
        out[0] = 5.0f * total;                     // LAMBDA_COORD * (...)
    }
}

extern "C" void kernel_launch(void* const* d_in, const int* in_sizes, int n_in,
                              void* d_out, int out_size, void* d_ws, size_t ws_size,
                              hipStream_t stream) {
    const float* P = (const float*)d_in[0];        // predictions f32
    const float* T = (const float*)d_in[1];        // targets f32
    float* out = (float*)d_out;

    float* sums   = (float*)d_ws;                  // NB floats (fully overwritten)
    int*   counts = (int*)((char*)d_ws + NB * 4);  // NB ints   (fully overwritten)

    yolo_part1<<<NB, BS, 0, stream>>>(P, T, sums, counts);
    yolo_part2<<<1, BS, 0, stream>>>(P, T, sums, counts, out);
}